// Round 1
// baseline (190.645 us; speedup 1.0000x reference)
//
#include <hip/hip_runtime.h>

// PINN beam residual: 1->16->16->2 tanh MLP with analytic 1st/2nd/3rd
// derivatives w.r.t. the scalar input. Outputs (u, w, wx, N, M, Q), each
// length n, concatenated.

constexpr float L_CONST  = 2.0f;
constexpr float EA_CONST = 1000.0f;
constexpr float EI_CONST = 100.0f;

__global__ __launch_bounds__(256) void pinn_kernel(
    const float* __restrict__ x,
    const float* __restrict__ W1, const float* __restrict__ b1,
    const float* __restrict__ W2, const float* __restrict__ b2,
    const float* __restrict__ W3, const float* __restrict__ b3,
    float* __restrict__ out, int n)
{
    __shared__ float sW1[16], sb1[16], sW2[256], sb2[16], sW3[32], sb3[2];
    {
        int t = threadIdx.x;
        if (t < 16) { sW1[t] = W1[t]; sb1[t] = b1[t]; sb2[t] = b2[t]; }
        if (t < 256) sW2[t] = W2[t];
        if (t < 32)  sW3[t] = W3[t];
        if (t < 2)   sb3[t] = b3[t];
    }
    __syncthreads();

    int idx = blockIdx.x * blockDim.x + threadIdx.x;
    if (idx >= n) return;

    float xs = x[idx] * (1.0f / L_CONST);

    // z2 and its first three derivatives w.r.t. xi (accumulators)
    float z2[16], z2p[16], z2pp[16], z2ppp[16];
#pragma unroll
    for (int j = 0; j < 16; ++j) {
        z2[j] = sb2[j]; z2p[j] = 0.0f; z2pp[j] = 0.0f; z2ppp[j] = 0.0f;
    }

#pragma unroll
    for (int i = 0; i < 16; ++i) {
        float w1 = sW1[i];
        float c  = w1 * (1.0f / L_CONST);      // dz1/dxi (constant)
        float t  = tanhf(w1 * xs + sb1[i]);
        float p  = 1.0f - t * t;               // sech^2
        float a    = t;
        float ap   = p * c;
        float app  = -2.0f * t * p * c * c;
        float appp = -2.0f * p * (1.0f - 3.0f * t * t) * c * c * c;
#pragma unroll
        for (int j = 0; j < 16; ++j) {
            float wji = sW2[j * 16 + i];       // broadcast LDS read
            z2[j]    = fmaf(wji, a,    z2[j]);
            z2p[j]   = fmaf(wji, ap,   z2p[j]);
            z2pp[j]  = fmaf(wji, app,  z2pp[j]);
            z2ppp[j] = fmaf(wji, appp, z2ppp[j]);
        }
    }

    float u = sb3[0], w = sb3[1];
    float up = 0.0f, wp = 0.0f, wpp = 0.0f, wppp = 0.0f;
#pragma unroll
    for (int j = 0; j < 16; ++j) {
        float t = tanhf(z2[j]);
        float p = 1.0f - t * t;
        float zp = z2p[j], zpp = z2pp[j], zppp = z2ppp[j];
        float a2    = t;
        float a2p   = p * zp;
        float a2pp  = p * zpp - 2.0f * t * p * zp * zp;
        float a2ppp = p * zppp - 6.0f * t * p * zp * zpp
                      - 2.0f * p * (1.0f - 3.0f * t * t) * zp * zp * zp;
        float w30 = sW3[j], w31 = sW3[16 + j];
        u  = fmaf(w30, a2,  u);
        up = fmaf(w30, a2p, up);
        w    = fmaf(w31, a2,    w);
        wp   = fmaf(w31, a2p,   wp);
        wpp  = fmaf(w31, a2pp,  wpp);
        wppp = fmaf(w31, a2ppp, wppp);
    }

    float Nax = EA_CONST * (up + 0.5f * wp * wp);
    out[idx]         = u;
    out[n + idx]     = w;
    out[2 * n + idx] = wp;
    out[3 * n + idx] = Nax;
    out[4 * n + idx] = -EI_CONST * wpp;
    out[5 * n + idx] = -EI_CONST * wppp + Nax * wp;
}

extern "C" void kernel_launch(void* const* d_in, const int* in_sizes, int n_in,
                              void* d_out, int out_size, void* d_ws, size_t ws_size,
                              hipStream_t stream) {
    const float* x  = (const float*)d_in[0];
    const float* W1 = (const float*)d_in[1];
    const float* b1 = (const float*)d_in[2];
    const float* W2 = (const float*)d_in[3];
    const float* b2 = (const float*)d_in[4];
    const float* W3 = (const float*)d_in[5];
    const float* b3 = (const float*)d_in[6];
    float* out = (float*)d_out;

    int n = in_sizes[0];
    int block = 256;
    int grid = (n + block - 1) / block;
    pinn_kernel<<<grid, block, 0, stream>>>(x, W1, b1, W2, b2, W3, b3, out, n);
}

// Round 2
// 111.348 us; speedup vs baseline: 1.7122x; 1.7122x over previous
//
#include <hip/hip_runtime.h>

// PINN beam residual: 1->16->16->2 tanh MLP with analytic 1st/2nd/3rd
// derivatives w.r.t. the scalar input. Outputs (u, w, wx, N, M, Q), each
// length n, concatenated.
//
// R1: replaced libm tanhf (ocml: divides/branches, ~70% of VALU issue,
// 184 VGPR) with hardware exp2+rcp tanh: t = 1 - 2/(1+exp2(2*log2e*x)).
// Saturates correctly at +/-inf, ~1e-6 rel error vs 2.96 abs threshold.

constexpr float L_CONST  = 2.0f;
constexpr float EA_CONST = 1000.0f;
constexpr float EI_CONST = 100.0f;

__device__ __forceinline__ float fast_tanh(float x) {
    // tanh(x) = 1 - 2/(1 + e^{2x});  e^{2x} = 2^{x * 2*log2(e)}
    float e = __builtin_amdgcn_exp2f(x * 2.8853900817779268f);
    float r = __builtin_amdgcn_rcpf(1.0f + e);
    return fmaf(-2.0f, r, 1.0f);
}

__global__ __launch_bounds__(256) void pinn_kernel(
    const float* __restrict__ x,
    const float* __restrict__ W1, const float* __restrict__ b1,
    const float* __restrict__ W2, const float* __restrict__ b2,
    const float* __restrict__ W3, const float* __restrict__ b3,
    float* __restrict__ out, int n)
{
    __shared__ float sW1[16], sb1[16], sW2[256], sb2[16], sW3[32], sb3[2];
    {
        int t = threadIdx.x;
        if (t < 16) { sW1[t] = W1[t]; sb1[t] = b1[t]; sb2[t] = b2[t]; }
        if (t < 256) sW2[t] = W2[t];
        if (t < 32)  sW3[t] = W3[t];
        if (t < 2)   sb3[t] = b3[t];
    }
    __syncthreads();

    int idx = blockIdx.x * blockDim.x + threadIdx.x;
    if (idx >= n) return;

    float xs = x[idx] * (1.0f / L_CONST);

    // z2 and its first three derivatives w.r.t. xi (accumulators)
    float z2[16], z2p[16], z2pp[16], z2ppp[16];
#pragma unroll
    for (int j = 0; j < 16; ++j) {
        z2[j] = sb2[j]; z2p[j] = 0.0f; z2pp[j] = 0.0f; z2ppp[j] = 0.0f;
    }

#pragma unroll
    for (int i = 0; i < 16; ++i) {
        float w1 = sW1[i];
        float c  = w1 * (1.0f / L_CONST);      // dz1/dxi (constant)
        float t  = fast_tanh(fmaf(w1, xs, sb1[i]));
        float p  = 1.0f - t * t;               // sech^2
        float c2 = c * c;
        float a    = t;
        float ap   = p * c;
        float app  = -2.0f * t * p * c2;
        float appp = -2.0f * p * fmaf(-3.0f, t * t, 1.0f) * c2 * c;
#pragma unroll
        for (int j = 0; j < 16; ++j) {
            float wji = sW2[j * 16 + i];       // broadcast LDS read
            z2[j]    = fmaf(wji, a,    z2[j]);
            z2p[j]   = fmaf(wji, ap,   z2p[j]);
            z2pp[j]  = fmaf(wji, app,  z2pp[j]);
            z2ppp[j] = fmaf(wji, appp, z2ppp[j]);
        }
    }

    float u = sb3[0], w = sb3[1];
    float up = 0.0f, wp = 0.0f, wpp = 0.0f, wppp = 0.0f;
#pragma unroll
    for (int j = 0; j < 16; ++j) {
        float t = fast_tanh(z2[j]);
        float p = 1.0f - t * t;
        float zp = z2p[j], zpp = z2pp[j], zppp = z2ppp[j];
        float zp2 = zp * zp;
        float a2    = t;
        float a2p   = p * zp;
        float a2pp  = p * zpp - 2.0f * t * p * zp2;
        float a2ppp = p * zppp - 6.0f * t * p * zp * zpp
                      - 2.0f * p * fmaf(-3.0f, t * t, 1.0f) * zp2 * zp;
        float w30 = sW3[j], w31 = sW3[16 + j];
        u  = fmaf(w30, a2,  u);
        up = fmaf(w30, a2p, up);
        w    = fmaf(w31, a2,    w);
        wp   = fmaf(w31, a2p,   wp);
        wpp  = fmaf(w31, a2pp,  wpp);
        wppp = fmaf(w31, a2ppp, wppp);
    }

    float Nax = EA_CONST * fmaf(0.5f * wp, wp, up);
    out[idx]         = u;
    out[n + idx]     = w;
    out[2 * n + idx] = wp;
    out[3 * n + idx] = Nax;
    out[4 * n + idx] = -EI_CONST * wpp;
    out[5 * n + idx] = fmaf(Nax, wp, -EI_CONST * wppp);
}

extern "C" void kernel_launch(void* const* d_in, const int* in_sizes, int n_in,
                              void* d_out, int out_size, void* d_ws, size_t ws_size,
                              hipStream_t stream) {
    const float* x  = (const float*)d_in[0];
    const float* W1 = (const float*)d_in[1];
    const float* b1 = (const float*)d_in[2];
    const float* W2 = (const float*)d_in[3];
    const float* b2 = (const float*)d_in[4];
    const float* W3 = (const float*)d_in[5];
    const float* b3 = (const float*)d_in[6];
    float* out = (float*)d_out;

    int n = in_sizes[0];
    int block = 256;
    int grid = (n + block - 1) / block;
    pinn_kernel<<<grid, block, 0, stream>>>(x, W1, b1, W2, b2, W3, b3, out, n);
}

// Round 3
// 106.693 us; speedup vs baseline: 1.7869x; 1.0436x over previous
//
#include <hip/hip_runtime.h>

// PINN beam residual: 1->16->16->2 tanh MLP with analytic 1st/2nd/3rd
// derivatives w.r.t. the scalar input. Outputs (u, w, wx, N, M, Q) concat.
//
// R1: hw tanh (exp2+rcp)  -> 50us dispatch, VALU-issue-bound (~3600 cy/wave).
// R2: packed-fp32 experiment: all accumulators as float2 ext-vectors via
// __builtin_elementwise_fma -> v_pk_fma_f32 (VOP3P). W2 transposed in LDS so
// j-pairs are contiguous; layer-1 constants (c, -2c^2, -2c^3) precomputed in
// LDS. If CDNA4 packs at full rate, matvec issue halves (2048->1024 cy).

typedef float v2f __attribute__((ext_vector_type(2)));

constexpr float EA_CONST = 1000.0f;
constexpr float EI_CONST = 100.0f;
constexpr float TWO_LOG2E = 2.8853900817779268f;

__device__ __forceinline__ float fast_tanh(float x) {
    float e = __builtin_amdgcn_exp2f(x * TWO_LOG2E);
    float r = __builtin_amdgcn_rcpf(1.0f + e);
    return fmaf(-2.0f, r, 1.0f);
}

__device__ __forceinline__ v2f fast_tanh2(v2f x) {
    v2f e, r;
    e.x = __builtin_amdgcn_exp2f(x.x * TWO_LOG2E);
    e.y = __builtin_amdgcn_exp2f(x.y * TWO_LOG2E);
    r.x = __builtin_amdgcn_rcpf(1.0f + e.x);
    r.y = __builtin_amdgcn_rcpf(1.0f + e.y);
    v2f mtwo = {-2.0f, -2.0f}, one = {1.0f, 1.0f};
    return __builtin_elementwise_fma(mtwo, r, one);
}

__global__ __launch_bounds__(256) void pinn_kernel(
    const float* __restrict__ x,
    const float* __restrict__ W1, const float* __restrict__ b1,
    const float* __restrict__ W2, const float* __restrict__ b2,
    const float* __restrict__ W3, const float* __restrict__ b3,
    float* __restrict__ out, int n)
{
    __shared__ float sC[16], sK2[16], sK3[16], sb1[16], sb2[16];
    __shared__ float sW2t[256];   // transposed: sW2t[i*16+j] = W2[j*16+i]
    __shared__ float sW3[32], sb3[2];
    {
        int t = threadIdx.x;
        if (t < 16) {
            float c = W1[t] * 0.5f;            // W1_i / L, L = 2
            sC[t]  = c;
            sK2[t] = -2.0f * c * c;
            sK3[t] = -2.0f * c * c * c;
            sb1[t] = b1[t];
            sb2[t] = b2[t];
        }
        if (t < 256) { int j = t >> 4, i = t & 15; sW2t[i * 16 + j] = W2[t]; }
        if (t < 32)  sW3[t] = W3[t];
        if (t < 2)   sb3[t] = b3[t];
    }
    __syncthreads();

    int idx = blockIdx.x * blockDim.x + threadIdx.x;
    if (idx >= n) return;

    float xr = x[idx];                          // z1 = (W1/L)*x + b1 = c*x + b1

    v2f z2v[8], z2pv[8], z2ppv[8], z2pppv[8];
    const v2f* sb2v = (const v2f*)sb2;
#pragma unroll
    for (int jp = 0; jp < 8; ++jp) {
        z2v[jp] = sb2v[jp];
        z2pv[jp] = (v2f){0.0f, 0.0f};
        z2ppv[jp] = (v2f){0.0f, 0.0f};
        z2pppv[jp] = (v2f){0.0f, 0.0f};
    }

#pragma unroll
    for (int i = 0; i < 16; ++i) {
        float c = sC[i], k2 = sK2[i], k3 = sK3[i];
        float t = fast_tanh(fmaf(c, xr, sb1[i]));
        float t2 = t * t;
        float p = 1.0f - t2;
        float tp = t * p;
        float g = fmaf(-3.0f, t2, 1.0f);
        float a = t, ap = p * c, app = tp * k2, appp = (p * g) * k3;
        v2f av = {a, a}, apv = {ap, ap}, appv = {app, app}, apppv = {appp, appp};
        const v2f* row = (const v2f*)(sW2t + i * 16);
#pragma unroll
        for (int jp = 0; jp < 8; ++jp) {
            v2f wv = row[jp];
            z2v[jp]    = __builtin_elementwise_fma(wv, av,    z2v[jp]);
            z2pv[jp]   = __builtin_elementwise_fma(wv, apv,   z2pv[jp]);
            z2ppv[jp]  = __builtin_elementwise_fma(wv, appv,  z2ppv[jp]);
            z2pppv[jp] = __builtin_elementwise_fma(wv, apppv, z2pppv[jp]);
        }
    }

    const v2f* w30v = (const v2f*)sW3;
    const v2f* w31v = (const v2f*)(sW3 + 16);
    v2f uv = {0, 0}, upv = {0, 0}, wv_ = {0, 0}, wpv = {0, 0}, wppv = {0, 0}, wpppv = {0, 0};
    const v2f mtwo = {-2.0f, -2.0f}, msix = {-6.0f, -6.0f};
#pragma unroll
    for (int jp = 0; jp < 8; ++jp) {
        v2f z = z2v[jp], zp = z2pv[jp], zpp = z2ppv[jp], zppp = z2pppv[jp];
        v2f t = fast_tanh2(z);
        v2f t2 = t * t;
        v2f p; p.x = 1.0f - t2.x; p.y = 1.0f - t2.y;
        v2f tp = t * p;
        v2f g; g.x = fmaf(-3.0f, t2.x, 1.0f); g.y = fmaf(-3.0f, t2.y, 1.0f);
        v2f a2p = p * zp;
        v2f zp2 = zp * zp;
        v2f m = tp * zp2;
        v2f pzpp = p * zpp;
        v2f a2pp = __builtin_elementwise_fma(mtwo, m, pzpp);
        v2f h1 = zp * zpp;
        v2f s1 = tp * h1;
        v2f pz3 = p * zppp;
        v2f m1 = __builtin_elementwise_fma(msix, s1, pz3);
        v2f pg = p * g;
        v2f h2 = zp2 * zp;
        v2f s2 = pg * h2;
        v2f a2ppp = __builtin_elementwise_fma(mtwo, s2, m1);
        v2f w0 = w30v[jp], w1 = w31v[jp];
        uv    = __builtin_elementwise_fma(w0, t,     uv);
        upv   = __builtin_elementwise_fma(w0, a2p,   upv);
        wv_   = __builtin_elementwise_fma(w1, t,     wv_);
        wpv   = __builtin_elementwise_fma(w1, a2p,   wpv);
        wppv  = __builtin_elementwise_fma(w1, a2pp,  wppv);
        wpppv = __builtin_elementwise_fma(w1, a2ppp, wpppv);
    }

    float u    = sb3[0] + uv.x + uv.y;
    float w    = sb3[1] + wv_.x + wv_.y;
    float up   = upv.x + upv.y;
    float wp   = wpv.x + wpv.y;
    float wpp  = wppv.x + wppv.y;
    float wppp = wpppv.x + wpppv.y;

    float Nax = EA_CONST * fmaf(0.5f * wp, wp, up);
    out[idx]         = u;
    out[n + idx]     = w;
    out[2 * n + idx] = wp;
    out[3 * n + idx] = Nax;
    out[4 * n + idx] = -EI_CONST * wpp;
    out[5 * n + idx] = fmaf(Nax, wp, -EI_CONST * wppp);
}

extern "C" void kernel_launch(void* const* d_in, const int* in_sizes, int n_in,
                              void* d_out, int out_size, void* d_ws, size_t ws_size,
                              hipStream_t stream) {
    const float* x  = (const float*)d_in[0];
    const float* W1 = (const float*)d_in[1];
    const float* b1 = (const float*)d_in[2];
    const float* W2 = (const float*)d_in[3];
    const float* b2 = (const float*)d_in[4];
    const float* W3 = (const float*)d_in[5];
    const float* b3 = (const float*)d_in[6];
    float* out = (float*)d_out;

    int n = in_sizes[0];
    int block = 256;
    int grid = (n + block - 1) / block;
    pinn_kernel<<<grid, block, 0, stream>>>(x, W1, b1, W2, b2, W3, b3, out, n);
}

// Round 4
// 103.728 us; speedup vs baseline: 1.8379x; 1.0286x over previous
//
#include <hip/hip_runtime.h>

// PINN beam residual: 1->16->16->2 tanh MLP with analytic 1st/2nd/3rd
// derivatives w.r.t. the scalar input. Outputs (u, w, wx, N, M, Q) concat.
//
// R1: hw tanh (exp2+rcp)      -> 50us, VALU-issue-bound.
// R2: v_pk_fma_f32 packed pairs-> 44.6us; VALU issue halved (busy 95->60%)
//     but LDS issue (128 ds_read_b64/thread) + stalls became the floor.
// R3: 2 points per thread packed into pk-register halves:
//     - all pointwise math (layer1, tanh, derivative combos, epilogue) is
//       naturally 2-wide -> per-point pointwise issue halves
//     - weight is the splat operand -> W2 read row-major (no transpose, no
//       bank-conflict write) as ds_read_b128: 64 b128 / 2 points = 32/pt
//     - j-outer loop with fused epilogue; z2 never stored
//     - per-i and per-j constants packed into single b128 LDS reads

typedef float v2f __attribute__((ext_vector_type(2)));
typedef float v4f __attribute__((ext_vector_type(4)));

constexpr float EA_CONST = 1000.0f;
constexpr float EI_CONST = 100.0f;
constexpr float TWO_LOG2E = 2.8853900817779268f;

__device__ __forceinline__ v2f splat2(float s) { v2f r; r.x = s; r.y = s; return r; }
__device__ __forceinline__ v2f pkfma(v2f a, v2f b, v2f c) {
    return __builtin_elementwise_fma(a, b, c);
}

__device__ __forceinline__ v2f fast_tanh2(v2f x) {
    v2f e, r;
    e.x = __builtin_amdgcn_exp2f(x.x * TWO_LOG2E);
    e.y = __builtin_amdgcn_exp2f(x.y * TWO_LOG2E);
    r.x = __builtin_amdgcn_rcpf(1.0f + e.x);
    r.y = __builtin_amdgcn_rcpf(1.0f + e.y);
    return pkfma(splat2(-2.0f), r, splat2(1.0f));
}

__global__ __launch_bounds__(256) void pinn_kernel(
    const float* __restrict__ x,
    const float* __restrict__ W1, const float* __restrict__ b1,
    const float* __restrict__ W2, const float* __restrict__ b2,
    const float* __restrict__ W3, const float* __restrict__ b3,
    float* __restrict__ out, int n)
{
    // sL1[i] = {c_i, -2c^2, -2c^3, b1_i};  sJC[j] = {W3[0][j], W3[1][j], b2[j], 0}
    __shared__ v4f sL1[16];
    __shared__ v4f sJC[16];
    __shared__ float sW2[256];
    __shared__ float sb3[2];
    {
        int t = threadIdx.x;
        if (t < 16) {
            float c = W1[t] * 0.5f;            // W1_i / L, L = 2
            v4f l1; l1.x = c; l1.y = -2.0f * c * c; l1.z = -2.0f * c * c * c; l1.w = b1[t];
            sL1[t] = l1;
            v4f jc; jc.x = W3[t]; jc.y = W3[16 + t]; jc.z = b2[t]; jc.w = 0.0f;
            sJC[t] = jc;
        }
        sW2[t] = W2[t];
        if (t < 2) sb3[t] = b3[t];
    }
    __syncthreads();

    int tid  = threadIdx.x;
    int i0   = blockIdx.x * 512 + tid;
    int i1   = i0 + 256;
    bool g0 = i0 < n, g1 = i1 < n;
    v2f xp;
    xp.x = g0 ? x[i0] : 0.0f;
    xp.y = g1 ? x[i1] : 0.0f;

    // ---- Layer 1: activations + 3 derivatives for all 16 units, 2 points ----
    v2f A[16], Ap[16], App[16], Appp[16];
#pragma unroll
    for (int i = 0; i < 16; ++i) {
        v4f l1 = sL1[i];
        float c = l1.x, k2 = l1.y, k3 = l1.z, bb = l1.w;
        v2f z  = pkfma(splat2(c), xp, splat2(bb));
        v2f t  = fast_tanh2(z);
        v2f t2 = t * t;
        v2f p  = pkfma(splat2(-1.0f), t2, splat2(1.0f));   // 1 - t^2
        v2f tp = t * p;
        v2f g  = pkfma(splat2(-3.0f), t2, splat2(1.0f));   // 1 - 3t^2
        A[i]    = t;
        Ap[i]   = p * splat2(c);
        App[i]  = tp * splat2(k2);
        Appp[i] = (p * g) * splat2(k3);
    }

    // ---- Layer 2 + head, fused per output unit j ----
    v2f u = splat2(0.0f), w = splat2(0.0f);
    v2f up = splat2(0.0f), wp = splat2(0.0f), wpp = splat2(0.0f), wppp = splat2(0.0f);
#pragma unroll
    for (int j = 0; j < 16; ++j) {
        const v4f* row = (const v4f*)(sW2 + j * 16);
        v4f r0 = row[0], r1 = row[1], r2 = row[2], r3 = row[3];
        float wr[16] = { r0.x, r0.y, r0.z, r0.w, r1.x, r1.y, r1.z, r1.w,
                         r2.x, r2.y, r2.z, r2.w, r3.x, r3.y, r3.z, r3.w };
        v4f jc = sJC[j];
        v2f z    = splat2(jc.z);
        v2f zp   = splat2(0.0f);
        v2f zpp  = splat2(0.0f);
        v2f zppp = splat2(0.0f);
#pragma unroll
        for (int i = 0; i < 16; ++i) {
            v2f wv = splat2(wr[i]);
            z    = pkfma(wv, A[i],    z);
            zp   = pkfma(wv, Ap[i],   zp);
            zpp  = pkfma(wv, App[i],  zpp);
            zppp = pkfma(wv, Appp[i], zppp);
        }
        v2f t  = fast_tanh2(z);
        v2f t2 = t * t;
        v2f p  = pkfma(splat2(-1.0f), t2, splat2(1.0f));
        v2f tp = t * p;
        v2f g  = pkfma(splat2(-3.0f), t2, splat2(1.0f));
        v2f a2p   = p * zp;
        v2f zp2   = zp * zp;
        v2f a2pp  = pkfma(splat2(-2.0f), tp * zp2, p * zpp);
        v2f m1    = pkfma(splat2(-6.0f), tp * (zp * zpp), p * zppp);
        v2f a2ppp = pkfma(splat2(-2.0f), (p * g) * (zp2 * zp), m1);
        v2f w30 = splat2(jc.x), w31 = splat2(jc.y);
        u    = pkfma(w30, t,     u);
        up   = pkfma(w30, a2p,   up);
        w    = pkfma(w31, t,     w);
        wp   = pkfma(w31, a2p,   wp);
        wpp  = pkfma(w31, a2pp,  wpp);
        wppp = pkfma(w31, a2ppp, wppp);
    }

    u = u + splat2(sb3[0]);
    w = w + splat2(sb3[1]);

    v2f Nax = splat2(EA_CONST) * pkfma(wp * splat2(0.5f), wp, up);
    v2f M   = splat2(-EI_CONST) * wpp;
    v2f Q   = pkfma(Nax, wp, splat2(-EI_CONST) * wppp);

    if (g0) {
        out[i0]         = u.x;
        out[n + i0]     = w.x;
        out[2 * n + i0] = wp.x;
        out[3 * n + i0] = Nax.x;
        out[4 * n + i0] = M.x;
        out[5 * n + i0] = Q.x;
    }
    if (g1) {
        out[i1]         = u.y;
        out[n + i1]     = w.y;
        out[2 * n + i1] = wp.y;
        out[3 * n + i1] = Nax.y;
        out[4 * n + i1] = M.y;
        out[5 * n + i1] = Q.y;
    }
}

extern "C" void kernel_launch(void* const* d_in, const int* in_sizes, int n_in,
                              void* d_out, int out_size, void* d_ws, size_t ws_size,
                              hipStream_t stream) {
    const float* x  = (const float*)d_in[0];
    const float* W1 = (const float*)d_in[1];
    const float* b1 = (const float*)d_in[2];
    const float* W2 = (const float*)d_in[3];
    const float* b2 = (const float*)d_in[4];
    const float* W3 = (const float*)d_in[5];
    const float* b3 = (const float*)d_in[6];
    float* out = (float*)d_out;

    int n = in_sizes[0];
    int block = 256;
    int grid = (n + 2 * block - 1) / (2 * block);
    pinn_kernel<<<grid, block, 0, stream>>>(x, W1, b1, W2, b2, W3, b3, out, n);
}